// Round 1
// baseline (267.632 us; speedup 1.0000x reference)
//
#include <hip/hip_runtime.h>

typedef __attribute__((ext_vector_type(8))) short bf16x8;
typedef __attribute__((ext_vector_type(4))) float f32x4;

#define MFMA16(a,b,c) __builtin_amdgcn_mfma_f32_16x16x32_bf16(a,b,c,0,0,0)

__device__ __forceinline__ unsigned short f2bf(float f){
  unsigned int u = __float_as_uint(f);
  unsigned int r = (u + 0x7fffu + ((u >> 16) & 1u)) >> 16;
  return (unsigned short)r;
}
__device__ __forceinline__ float bf2f(unsigned short u){
  return __uint_as_float(((unsigned int)u) << 16);
}

// ---------------- prep: f32 -> bf16 conversions ----------------
// regions: [0,1M): s ; [1M,5M): wq|wk|wv|wg packed ; [5M,6M): wo
__global__ __launch_bounds__(256) void prep_kernel(
    const float* __restrict__ s, const float* __restrict__ wq,
    const float* __restrict__ wk, const float* __restrict__ wv,
    const float* __restrict__ wg, const float* __restrict__ wo,
    unsigned short* __restrict__ sb, unsigned short* __restrict__ Wp,
    unsigned short* __restrict__ wob)
{
  const size_t M1 = 1u << 20;
  size_t base = ((size_t)blockIdx.x * 256 + threadIdx.x) * 4;
  const float* src; unsigned short* dst; size_t off;
  if (base < M1) { src = s; dst = sb; off = base; }
  else if (base < 5*M1) {
    size_t r = base - M1; int wsel = (int)(r >> 20);
    const float* wsrc0 = (wsel == 0) ? wq : (wsel == 1) ? wk : (wsel == 2) ? wv : wg;
    src = wsrc0; dst = Wp + ((size_t)wsel << 20); off = r & (M1 - 1);
  } else { src = wo; dst = wob; off = base - 5*M1; }
  float4 v = *(const float4*)(src + off);
  ushort4 o4;
  o4.x = f2bf(v.x); o4.y = f2bf(v.y); o4.z = f2bf(v.z); o4.w = f2bf(v.w);
  *(ushort4*)(dst + off) = o4;
}

// ---------------- wz prep: wz' = wz*w (bf16), c1=sum(wz*w), c2=sum(wz*b) ----------------
__global__ __launch_bounds__(256) void wzprep_kernel(
    const float* __restrict__ wz, const float* __restrict__ znw,
    const float* __restrict__ znb, unsigned short* __restrict__ wzp,
    float* __restrict__ c12)
{
  __shared__ float r1[256], r2[256];
  int t = threadIdx.x; int h = t >> 4; int k0 = (t & 15) * 8;
  float p1 = 0.f, p2 = 0.f;
  for (int e = 0; e < 8; e++) {
    float wv = wz[h*128 + k0 + e];
    float w = znw[k0 + e], b = znb[k0 + e];
    wzp[h*128 + k0 + e] = f2bf(wv * w);
    p1 += wv * w; p2 += wv * b;
  }
  r1[t] = p1; r2[t] = p2;
  __syncthreads();
  if ((t & 15) == 0) {
    float s1 = 0.f, s2 = 0.f;
    for (int i = 0; i < 16; i++) { s1 += r1[t + i]; s2 += r2[t + i]; }
    c12[2*h] = s1; c12[2*h + 1] = s2;
  }
}

// ---------------- bias: bias[h][i][j] = LN(z[i,j,:]) . wz[h,:] ----------------
// per wave: 16 positions j; MFMA A = wz' [16h x 128k], B = raw z bf16 [128k x 16j]
// bias_h = rs*dot - mu*rs*c1_h + c2_h
__global__ __launch_bounds__(256) void bias_kernel(
    const float* __restrict__ z, const unsigned short* __restrict__ wzp,
    const float* __restrict__ c12, float* __restrict__ bias)
{
  int wv = threadIdx.x >> 6, lane = threadIdx.x & 63;
  int jl = lane & 15, g = lane >> 4;
  int blk = blockIdx.x;
  int i = blk >> 4;
  int j = (blk & 15) * 64 + wv * 16 + jl;

  bf16x8 af[4];
  #pragma unroll
  for (int mk = 0; mk < 4; mk++)
    af[mk] = *(const bf16x8*)(wzp + jl*128 + mk*32 + g*8);

  const float* zp = z + ((size_t)i * 1024 + j) * 128;
  float4 zv[8];
  #pragma unroll
  for (int mk = 0; mk < 4; mk++) {
    zv[2*mk]   = *(const float4*)(zp + mk*32 + g*8);
    zv[2*mk+1] = *(const float4*)(zp + mk*32 + g*8 + 4);
  }
  float sum = 0.f, sq = 0.f;
  #pragma unroll
  for (int t = 0; t < 8; t++) {
    float4 v = zv[t];
    sum += v.x + v.y + v.z + v.w;
    sq = fmaf(v.x, v.x, fmaf(v.y, v.y, fmaf(v.z, v.z, fmaf(v.w, v.w, sq))));
  }
  sum += __shfl_xor(sum, 16); sum += __shfl_xor(sum, 32);
  sq  += __shfl_xor(sq, 16);  sq  += __shfl_xor(sq, 32);
  float mu = sum * (1.f/128.f);
  float var = sq * (1.f/128.f) - mu * mu;
  float rs = rsqrtf(var + 1e-5f);

  f32x4 D = {0.f, 0.f, 0.f, 0.f};
  #pragma unroll
  for (int mk = 0; mk < 4; mk++) {
    float4 a = zv[2*mk], b = zv[2*mk+1];
    bf16x8 t;
    t[0] = (short)f2bf(a.x); t[1] = (short)f2bf(a.y);
    t[2] = (short)f2bf(a.z); t[3] = (short)f2bf(a.w);
    t[4] = (short)f2bf(b.x); t[5] = (short)f2bf(b.y);
    t[6] = (short)f2bf(b.z); t[7] = (short)f2bf(b.w);
    D = MFMA16(af[mk], t, D);
  }
  #pragma unroll
  for (int r = 0; r < 4; r++) {
    int h = g*4 + r;
    float c1 = c12[2*h], c2 = c12[2*h + 1];
    float bvv = rs * D[r] - mu * rs * c1 + c2;
    bias[(size_t)h * 1048576 + (size_t)i * 1024 + j] = bvv;
  }
}

// ---------------- bf16 GEMM: C[M][N] = A[M][K] * B[N][K]^T ----------------
// MODE 0: projection epilogue (q,k,vT,g) ; MODE 1: f32 store
template<int MODE>
__global__ __launch_bounds__(256) void gemm_bf16(
    const unsigned short* __restrict__ A, const unsigned short* __restrict__ Bm,
    int M, int N, int K,
    const float* __restrict__ bq,
    unsigned short* __restrict__ qb, unsigned short* __restrict__ kb,
    unsigned short* __restrict__ vT, unsigned short* __restrict__ gb,
    float* __restrict__ outF)
{
  int lane = threadIdx.x & 63;
  int w = threadIdx.x >> 6;
  int lr = lane & 15, lg = lane >> 4;
  int row0 = blockIdx.y * 128 + (w & 1) * 64;
  int col0 = blockIdx.x * 128 + (w >> 1) * 64;
  f32x4 acc[4][4] = {};
  for (int kk = 0; kk < K; kk += 32) {
    bf16x8 af[4], bfr[4];
    #pragma unroll
    for (int t = 0; t < 4; t++)
      af[t] = *(const bf16x8*)(A + (size_t)(row0 + t*16 + lr) * K + kk + lg*8);
    #pragma unroll
    for (int t = 0; t < 4; t++)
      bfr[t] = *(const bf16x8*)(Bm + (size_t)(col0 + t*16 + lr) * K + kk + lg*8);
    #pragma unroll
    for (int a = 0; a < 4; a++)
      #pragma unroll
      for (int b = 0; b < 4; b++)
        acc[a][b] = MFMA16(af[a], bfr[b], acc[a][b]);
  }
  #pragma unroll
  for (int a = 0; a < 4; a++)
    #pragma unroll
    for (int b = 0; b < 4; b++)
      #pragma unroll
      for (int r = 0; r < 4; r++) {
        int m = row0 + a*16 + lg*4 + r;
        int n = col0 + b*16 + lr;
        float v = acc[a][b][r];
        if (MODE == 0) {
          if (n < 1024)      { v = (v + bq[n]) * 0.125f; qb[(size_t)m*1024 + n] = f2bf(v); }
          else if (n < 2048) { kb[(size_t)m*1024 + (n-1024)] = f2bf(v); }
          else if (n < 3072) { vT[(size_t)(n-2048)*1024 + m] = f2bf(v); }
          else               { float sg = 1.f / (1.f + __expf(-v)); gb[(size_t)m*1024 + (n-3072)] = f2bf(sg); }
        } else {
          outF[(size_t)m * N + n] = v;
        }
      }
}

// ---------------- attention: flash-style, 1 wave per (head, 16 queries) ----------------
__global__ __launch_bounds__(64) void attn_kernel(
    const unsigned short* __restrict__ qb, const unsigned short* __restrict__ kb,
    const unsigned short* __restrict__ vT, const unsigned short* __restrict__ gb,
    const float* __restrict__ bias, unsigned short* __restrict__ og)
{
  __shared__ unsigned short P[16 * 72];   // P[q-local][j-local], stride 72 (bank-spread)
  int lane = threadIdx.x;
  int jl = lane & 15, g = lane >> 4;
  int q0 = blockIdx.x * 16;
  int h = blockIdx.y;

  bf16x8 aq[2];
  #pragma unroll
  for (int kh = 0; kh < 2; kh++)
    aq[kh] = *(const bf16x8*)(qb + (size_t)(q0 + jl)*1024 + h*64 + kh*32 + g*8);

  f32x4 od[4] = {};
  float m[4], ss[4];
  #pragma unroll
  for (int r = 0; r < 4; r++) { m[r] = -1e30f; ss[r] = 0.f; }
  const float* bp = bias + (size_t)h * 1048576;

  for (int jt = 0; jt < 1024; jt += 64) {
    f32x4 sc[4] = {};
    #pragma unroll
    for (int jb = 0; jb < 4; jb++)
      #pragma unroll
      for (int kh = 0; kh < 2; kh++) {
        bf16x8 bk = *(const bf16x8*)(kb + (size_t)(jt + jb*16 + jl)*1024 + h*64 + kh*32 + g*8);
        sc[jb] = MFMA16(aq[kh], bk, sc[jb]);
      }
    #pragma unroll
    for (int jb = 0; jb < 4; jb++)
      #pragma unroll
      for (int r = 0; r < 4; r++)
        sc[jb][r] += bp[(size_t)(q0 + g*4 + r)*1024 + jt + jb*16 + jl];

    float al[4];
    #pragma unroll
    for (int r = 0; r < 4; r++) {
      float mx = fmaxf(fmaxf(sc[0][r], sc[1][r]), fmaxf(sc[2][r], sc[3][r]));
      mx = fmaxf(mx, __shfl_xor(mx, 1));
      mx = fmaxf(mx, __shfl_xor(mx, 2));
      mx = fmaxf(mx, __shfl_xor(mx, 4));
      mx = fmaxf(mx, __shfl_xor(mx, 8));
      float mn = fmaxf(m[r], mx);
      float a = __expf(m[r] - mn);
      m[r] = mn; al[r] = a;
      float rsum = 0.f;
      #pragma unroll
      for (int jb = 0; jb < 4; jb++) {
        float p = __expf(sc[jb][r] - mn);
        sc[jb][r] = p; rsum += p;
      }
      ss[r] = ss[r] * a + rsum;
    }
    #pragma unroll
    for (int db = 0; db < 4; db++)
      #pragma unroll
      for (int r = 0; r < 4; r++) od[db][r] *= al[r];

    #pragma unroll
    for (int jb = 0; jb < 4; jb++)
      #pragma unroll
      for (int r = 0; r < 4; r++)
        P[(g*4 + r)*72 + jb*16 + jl] = f2bf(sc[jb][r]);
    // same-wave DS ops execute in order; compiler inserts lgkmcnt for the reads

    #pragma unroll
    for (int jh = 0; jh < 2; jh++) {
      bf16x8 ap = *(const bf16x8*)(&P[jl*72 + jh*32 + g*8]);
      #pragma unroll
      for (int db = 0; db < 4; db++) {
        bf16x8 bv = *(const bf16x8*)(vT + (size_t)(h*64 + db*16 + jl)*1024 + jt + jh*32 + g*8);
        od[db] = MFMA16(ap, bv, od[db]);
      }
    }
  }

  #pragma unroll
  for (int r = 0; r < 4; r++) {
    ss[r] += __shfl_xor(ss[r], 1); ss[r] += __shfl_xor(ss[r], 2);
    ss[r] += __shfl_xor(ss[r], 4); ss[r] += __shfl_xor(ss[r], 8);
    ss[r] = 1.f / ss[r];
  }
  #pragma unroll
  for (int db = 0; db < 4; db++)
    #pragma unroll
    for (int r = 0; r < 4; r++) {
      int q = q0 + g*4 + r;
      int d = h*64 + db*16 + jl;
      float o = od[db][r] * ss[r];
      float gv = bf2f(gb[(size_t)q*1024 + d]);
      og[(size_t)q*1024 + d] = f2bf(o * gv);
    }
}

extern "C" void kernel_launch(void* const* d_in, const int* in_sizes, int n_in,
                              void* d_out, int out_size, void* d_ws, size_t ws_size,
                              hipStream_t stream) {
  const float* s   = (const float*)d_in[0];
  const float* z   = (const float*)d_in[1];
  const float* wq  = (const float*)d_in[2];
  const float* bq  = (const float*)d_in[3];
  const float* wk  = (const float*)d_in[4];
  const float* wv  = (const float*)d_in[5];
  const float* wg  = (const float*)d_in[6];
  const float* znw = (const float*)d_in[7];
  const float* znb = (const float*)d_in[8];
  const float* wz  = (const float*)d_in[9];
  const float* wo  = (const float*)d_in[10];
  float* out = (float*)d_out;

  char* ws = (char*)d_ws;
  // workspace layout (~86 MB total)
  float*          biasb = (float*)ws;                                  // 64 MB
  unsigned short* qbuf  = (unsigned short*)(ws + ((size_t)64 << 20));  // 2 MB
  unsigned short* kbuf  = (unsigned short*)(ws + ((size_t)66 << 20));  // 2 MB
  unsigned short* vTb   = (unsigned short*)(ws + ((size_t)68 << 20));  // 2 MB
  unsigned short* gbuf  = (unsigned short*)(ws + ((size_t)70 << 20));  // 2 MB
  unsigned short* ogb   = (unsigned short*)(ws + ((size_t)72 << 20));  // 2 MB
  unsigned short* sb    = (unsigned short*)(ws + ((size_t)74 << 20));  // 2 MB
  unsigned short* Wp    = (unsigned short*)(ws + ((size_t)76 << 20));  // 8 MB
  unsigned short* wob   = (unsigned short*)(ws + ((size_t)84 << 20));  // 2 MB
  unsigned short* wzp   = (unsigned short*)(ws + ((size_t)86 << 20));  // 4 KB
  float*          c12   = (float*)(ws + ((size_t)86 << 20) + 4096);    // 128 B

  prep_kernel<<<6144, 256, 0, stream>>>(s, wq, wk, wv, wg, wo, sb, Wp, wob);
  wzprep_kernel<<<1, 256, 0, stream>>>(wz, znw, znb, wzp, c12);
  bias_kernel<<<16384, 256, 0, stream>>>(z, wzp, c12, biasb);
  gemm_bf16<0><<<dim3(32, 8), 256, 0, stream>>>(sb, Wp, 1024, 4096, 1024, bq,
                                                qbuf, kbuf, vTb, gbuf, nullptr);
  attn_kernel<<<dim3(64, 16), 64, 0, stream>>>(qbuf, kbuf, vTb, gbuf, biasb, ogb);
  gemm_bf16<1><<<dim3(8, 8), 256, 0, stream>>>(ogb, wob, 1024, 1024, 1024, nullptr,
                                               nullptr, nullptr, nullptr, nullptr, out);
}

// Round 3
// 259.424 us; speedup vs baseline: 1.0316x; 1.0316x over previous
//
#include <hip/hip_runtime.h>

typedef __attribute__((ext_vector_type(8))) short bf16x8;
typedef __attribute__((ext_vector_type(4))) float f32x4;

#define MFMA16(a,b,c) __builtin_amdgcn_mfma_f32_16x16x32_bf16(a,b,c,0,0,0)

__device__ __forceinline__ unsigned short f2bf(float f){
  unsigned int u = __float_as_uint(f);
  unsigned int r = (u + 0x7fffu + ((u >> 16) & 1u)) >> 16;
  return (unsigned short)r;
}
__device__ __forceinline__ float bf2f(unsigned short u){
  return __uint_as_float(((unsigned int)u) << 16);
}

// ---------------- prep: f32 -> bf16 conversions ----------------
__global__ __launch_bounds__(256) void prep_kernel(
    const float* __restrict__ s, const float* __restrict__ wq,
    const float* __restrict__ wk, const float* __restrict__ wv,
    const float* __restrict__ wg, const float* __restrict__ wo,
    unsigned short* __restrict__ sb, unsigned short* __restrict__ Wp,
    unsigned short* __restrict__ wob)
{
  const size_t M1 = 1u << 20;
  size_t base = ((size_t)blockIdx.x * 256 + threadIdx.x) * 4;
  const float* src; unsigned short* dst; size_t off;
  if (base < M1) { src = s; dst = sb; off = base; }
  else if (base < 5*M1) {
    size_t r = base - M1; int wsel = (int)(r >> 20);
    const float* wsrc0 = (wsel == 0) ? wq : (wsel == 1) ? wk : (wsel == 2) ? wv : wg;
    src = wsrc0; dst = Wp + ((size_t)wsel << 20); off = r & (M1 - 1);
  } else { src = wo; dst = wob; off = base - 5*M1; }
  float4 v = *(const float4*)(src + off);
  ushort4 o4;
  o4.x = f2bf(v.x); o4.y = f2bf(v.y); o4.z = f2bf(v.z); o4.w = f2bf(v.w);
  *(ushort4*)(dst + off) = o4;
}

// ---------------- wz prep ----------------
__global__ __launch_bounds__(256) void wzprep_kernel(
    const float* __restrict__ wz, const float* __restrict__ znw,
    const float* __restrict__ znb, unsigned short* __restrict__ wzp,
    float* __restrict__ c12)
{
  __shared__ float r1[256], r2[256];
  int t = threadIdx.x; int h = t >> 4; int k0 = (t & 15) * 8;
  float p1 = 0.f, p2 = 0.f;
  for (int e = 0; e < 8; e++) {
    float wv = wz[h*128 + k0 + e];
    float w = znw[k0 + e], b = znb[k0 + e];
    wzp[h*128 + k0 + e] = f2bf(wv * w);
    p1 += wv * w; p2 += wv * b;
  }
  r1[t] = p1; r2[t] = p2;
  __syncthreads();
  if ((t & 15) == 0) {
    float s1 = 0.f, s2 = 0.f;
    for (int i = 0; i < 16; i++) { s1 += r1[t + i]; s2 += r2[t + i]; }
    c12[2*h] = s1; c12[2*h + 1] = s2;
  }
}

// ---------------- bias: bias[h][i][j] = LN(z[i,j,:]) . wz[h,:] ----------------
__global__ __launch_bounds__(256) void bias_kernel(
    const float* __restrict__ z, const unsigned short* __restrict__ wzp,
    const float* __restrict__ c12, float* __restrict__ bias)
{
  int wv = threadIdx.x >> 6, lane = threadIdx.x & 63;
  int jl = lane & 15, g = lane >> 4;
  int blk = blockIdx.x;
  int i = blk >> 4;
  int j = (blk & 15) * 64 + wv * 16 + jl;

  bf16x8 af[4];
  #pragma unroll
  for (int mk = 0; mk < 4; mk++)
    af[mk] = *(const bf16x8*)(wzp + jl*128 + mk*32 + g*8);

  const float* zp = z + ((size_t)i * 1024 + j) * 128;
  float4 zv[8];
  #pragma unroll
  for (int mk = 0; mk < 4; mk++) {
    zv[2*mk]   = *(const float4*)(zp + mk*32 + g*8);
    zv[2*mk+1] = *(const float4*)(zp + mk*32 + g*8 + 4);
  }
  float sum = 0.f, sq = 0.f;
  #pragma unroll
  for (int t = 0; t < 8; t++) {
    float4 v = zv[t];
    sum += v.x + v.y + v.z + v.w;
    sq = fmaf(v.x, v.x, fmaf(v.y, v.y, fmaf(v.z, v.z, fmaf(v.w, v.w, sq))));
  }
  sum += __shfl_xor(sum, 16); sum += __shfl_xor(sum, 32);
  sq  += __shfl_xor(sq, 16);  sq  += __shfl_xor(sq, 32);
  float mu = sum * (1.f/128.f);
  float var = sq * (1.f/128.f) - mu * mu;
  float rs = rsqrtf(var + 1e-5f);

  f32x4 D = {0.f, 0.f, 0.f, 0.f};
  #pragma unroll
  for (int mk = 0; mk < 4; mk++) {
    float4 a = zv[2*mk], b = zv[2*mk+1];
    bf16x8 t;
    t[0] = (short)f2bf(a.x); t[1] = (short)f2bf(a.y);
    t[2] = (short)f2bf(a.z); t[3] = (short)f2bf(a.w);
    t[4] = (short)f2bf(b.x); t[5] = (short)f2bf(b.y);
    t[6] = (short)f2bf(b.z); t[7] = (short)f2bf(b.w);
    D = MFMA16(af[mk], t, D);
  }
  #pragma unroll
  for (int r = 0; r < 4; r++) {
    int h = g*4 + r;
    float c1 = c12[2*h], c2 = c12[2*h + 1];
    float bvv = rs * D[r] - mu * rs * c1 + c2;
    bias[(size_t)h * 1048576 + (size_t)i * 1024 + j] = bvv;
  }
}

// ---------------- bf16 GEMM: C[M][N] = A[M][K] * B[N][K]^T ----------------
// wave tile 32x64 (acc 2x4); block = 4 waves (2 row x 2 col) = 64x128 tile
template<int MODE>
__global__ __launch_bounds__(256) void gemm_bf16(
    const unsigned short* __restrict__ A, const unsigned short* __restrict__ Bm,
    int M, int N, int K,
    const float* __restrict__ bq,
    unsigned short* __restrict__ qb, unsigned short* __restrict__ kb,
    unsigned short* __restrict__ vT, unsigned short* __restrict__ gb,
    float* __restrict__ outF)
{
  int lane = threadIdx.x & 63;
  int w = threadIdx.x >> 6;
  int lr = lane & 15, lg = lane >> 4;
  int row0 = blockIdx.y * 64 + (w & 1) * 32;
  int col0 = blockIdx.x * 128 + (w >> 1) * 64;
  f32x4 acc[2][4] = {};
  for (int kk = 0; kk < K; kk += 32) {
    bf16x8 af[2], bfr[4];
    #pragma unroll
    for (int t = 0; t < 2; t++)
      af[t] = *(const bf16x8*)(A + (size_t)(row0 + t*16 + lr) * K + kk + lg*8);
    #pragma unroll
    for (int t = 0; t < 4; t++)
      bfr[t] = *(const bf16x8*)(Bm + (size_t)(col0 + t*16 + lr) * K + kk + lg*8);
    #pragma unroll
    for (int a = 0; a < 2; a++)
      #pragma unroll
      for (int b = 0; b < 4; b++)
        acc[a][b] = MFMA16(af[a], bfr[b], acc[a][b]);
  }
  #pragma unroll
  for (int a = 0; a < 2; a++)
    #pragma unroll
    for (int b = 0; b < 4; b++)
      #pragma unroll
      for (int r = 0; r < 4; r++) {
        int m = row0 + a*16 + lg*4 + r;
        int n = col0 + b*16 + lr;
        float v = acc[a][b][r];
        if (MODE == 0) {
          if (n < 1024)      { v = (v + bq[n]) * 0.125f; qb[(size_t)m*1024 + n] = f2bf(v); }
          else if (n < 2048) { kb[(size_t)m*1024 + (n-1024)] = f2bf(v); }
          else if (n < 3072) { vT[(size_t)(n-2048)*1024 + m] = f2bf(v); }
          else               { float sg = 1.f / (1.f + __expf(-v)); gb[(size_t)m*1024 + (n-3072)] = f2bf(sg); }
        } else {
          outF[(size_t)m * N + n] = v;
        }
      }
}

// ---------------- attention: swapped-QK^T flash, 4-way j-split ----------------
// block = 256 thr = 4 waves; wave s handles j in [s*256, s*256+256)
// scores^T = mfma(K, Q): D rows = j, cols = q -> per-lane softmax state is scalar
__global__ __launch_bounds__(256) void attn_kernel(
    const unsigned short* __restrict__ qb, const unsigned short* __restrict__ kb,
    const unsigned short* __restrict__ vT, const float* __restrict__ bias,
    float* __restrict__ op, float* __restrict__ ml, float* __restrict__ ll)
{
  __shared__ unsigned short P[4][1024];   // per-wave 16q x 64j, XOR-swizzled 8-short blocks
  int lane = threadIdx.x & 63;
  int s = threadIdx.x >> 6;
  int jl = lane & 15, g = lane >> 4;
  int q0 = blockIdx.x * 16;
  int h = blockIdx.y;
  unsigned short* Pw = P[s];

  bf16x8 aq[2];
  #pragma unroll
  for (int kh = 0; kh < 2; kh++)
    aq[kh] = *(const bf16x8*)(qb + (size_t)(q0 + jl)*1024 + h*64 + kh*32 + g*8);

  f32x4 od[4] = {};
  float m = -1e30f, ss = 0.f;
  const float* bp = bias + (size_t)h * 1048576;

  for (int jt = s*256; jt < s*256 + 256; jt += 64) {
    f32x4 sc[4] = {};
    #pragma unroll
    for (int jb = 0; jb < 4; jb++)
      #pragma unroll
      for (int kh = 0; kh < 2; kh++) {
        bf16x8 bk = *(const bf16x8*)(kb + (size_t)(jt + jb*16 + jl)*1024 + h*64 + kh*32 + g*8);
        sc[jb] = MFMA16(bk, aq[kh], sc[jb]);   // swapped: rows=j, cols=q
      }
    #pragma unroll
    for (int jb = 0; jb < 4; jb++) {
      float4 bl = *(const float4*)(bp + (size_t)(q0 + jl)*1024 + jt + jb*16 + g*4);
      sc[jb][0] += bl.x; sc[jb][1] += bl.y; sc[jb][2] += bl.z; sc[jb][3] += bl.w;
    }

    // per-lane 16 values all belong to column q=jl; lanes jl, jl+16, jl+32, jl+48
    // each hold a disjoint quarter of the 64 j's for that q
    float mx = -1e30f;
    #pragma unroll
    for (int jb = 0; jb < 4; jb++)
      #pragma unroll
      for (int r = 0; r < 4; r++) mx = fmaxf(mx, sc[jb][r]);
    mx = fmaxf(mx, __shfl_xor(mx, 16));
    mx = fmaxf(mx, __shfl_xor(mx, 32));
    float mn = fmaxf(m, mx);
    float a = __expf(m - mn);
    m = mn;
    float rsum = 0.f;
    #pragma unroll
    for (int jb = 0; jb < 4; jb++) {
      short4 pk;
      float p0 = __expf(sc[jb][0] - mn); rsum += p0; pk.x = (short)f2bf(p0);
      float p1 = __expf(sc[jb][1] - mn); rsum += p1; pk.y = (short)f2bf(p1);
      float p2 = __expf(sc[jb][2] - mn); rsum += p2; pk.z = (short)f2bf(p2);
      float p3 = __expf(sc[jb][3] - mn); rsum += p3; pk.w = (short)f2bf(p3);
      int b = jb*2 + (g >> 1);
      int bpz = b ^ (jl & 7);
      *(short4*)(Pw + jl*64 + bpz*8 + (g & 1)*4) = pk;
    }
    ss = ss * a + rsum;   // per-lane partial: this lane's quarter of the j's

    float albc[4];
    #pragma unroll
    for (int r = 0; r < 4; r++) albc[r] = __shfl(a, g*4 + r);
    #pragma unroll
    for (int db = 0; db < 4; db++)
      #pragma unroll
      for (int r = 0; r < 4; r++) od[db][r] *= albc[r];

    // PV: A = P (rows q, k-dim j), B = v (cols d)
    #pragma unroll
    for (int jh = 0; jh < 2; jh++) {
      int b = jh*4 + g;
      int bpz = b ^ (jl & 7);
      bf16x8 ap = *(const bf16x8*)(Pw + jl*64 + bpz*8);
      #pragma unroll
      for (int db = 0; db < 4; db++) {
        bf16x8 bv = *(const bf16x8*)(vT + (size_t)(h*64 + db*16 + jl)*1024 + jt + jh*32 + g*8);
        od[db] = MFMA16(ap, bv, od[db]);
      }
    }
  }

  // FIX (round 3): ss held only this lane-group's quarter of the row sum.
  // Reduce across the 4 replicated groups (same jl, g=0..3) before writing l.
  ss += __shfl_xor(ss, 16);
  ss += __shfl_xor(ss, 32);

  // write partials: op[s][h][q][d], m/ss per (s,h,q)
  size_t base = ((size_t)(s*16 + h) * 1024);
  #pragma unroll
  for (int db = 0; db < 4; db++)
    #pragma unroll
    for (int r = 0; r < 4; r++) {
      int q = q0 + g*4 + r;
      op[(base + q)*64 + db*16 + jl] = od[db][r];
    }
  if (g == 0) {
    ml[base + q0 + jl] = m;
    ll[base + q0 + jl] = ss;
  }
}

// ---------------- combine: merge 4 j-split partials, gate, bf16 ----------------
__global__ __launch_bounds__(256) void combine_kernel(
    const float* __restrict__ op, const float* __restrict__ ml,
    const float* __restrict__ ll, const unsigned short* __restrict__ gb,
    unsigned short* __restrict__ og)
{
  int t = blockIdx.x * 256 + threadIdx.x;   // over 16h * 1024q * 16d4
  int d4 = t & 15;
  int q = (t >> 4) & 1023;
  int h = t >> 14;

  float mv[4], lv[4];
  float mstar = -1e30f;
  #pragma unroll
  for (int s = 0; s < 4; s++) {
    mv[s] = ml[(size_t)(s*16 + h)*1024 + q];
    lv[s] = ll[(size_t)(s*16 + h)*1024 + q];
    mstar = fmaxf(mstar, mv[s]);
  }
  float lsum = 0.f;
  float ws[4];
  #pragma unroll
  for (int s = 0; s < 4; s++) {
    ws[s] = __expf(mv[s] - mstar);
    lsum = fmaf(ws[s], lv[s], lsum);
  }
  float inv = 1.f / lsum;

  float4 o = {0.f, 0.f, 0.f, 0.f};
  #pragma unroll
  for (int s = 0; s < 4; s++) {
    float4 p = *(const float4*)(op + ((size_t)(s*16 + h)*1024 + q)*64 + d4*4);
    o.x = fmaf(ws[s], p.x, o.x); o.y = fmaf(ws[s], p.y, o.y);
    o.z = fmaf(ws[s], p.z, o.z); o.w = fmaf(ws[s], p.w, o.w);
  }
  ushort4 gv = *(const ushort4*)(gb + (size_t)q*1024 + h*64 + d4*4);
  ushort4 r;
  r.x = f2bf(o.x * inv * bf2f(gv.x));
  r.y = f2bf(o.y * inv * bf2f(gv.y));
  r.z = f2bf(o.z * inv * bf2f(gv.z));
  r.w = f2bf(o.w * inv * bf2f(gv.w));
  *(ushort4*)(og + (size_t)q*1024 + h*64 + d4*4) = r;
}

extern "C" void kernel_launch(void* const* d_in, const int* in_sizes, int n_in,
                              void* d_out, int out_size, void* d_ws, size_t ws_size,
                              hipStream_t stream) {
  const float* s   = (const float*)d_in[0];
  const float* z   = (const float*)d_in[1];
  const float* wq  = (const float*)d_in[2];
  const float* bq  = (const float*)d_in[3];
  const float* wk  = (const float*)d_in[4];
  const float* wv  = (const float*)d_in[5];
  const float* wg  = (const float*)d_in[6];
  const float* znw = (const float*)d_in[7];
  const float* znb = (const float*)d_in[8];
  const float* wz  = (const float*)d_in[9];
  const float* wo  = (const float*)d_in[10];
  float* out = (float*)d_out;

  char* ws = (char*)d_ws;
  float*          biasb = (float*)ws;                                  // 64 MB
  unsigned short* qbuf  = (unsigned short*)(ws + ((size_t)64 << 20));  // 2 MB
  unsigned short* kbuf  = (unsigned short*)(ws + ((size_t)66 << 20));  // 2 MB
  unsigned short* vTb   = (unsigned short*)(ws + ((size_t)68 << 20));  // 2 MB
  unsigned short* gbuf  = (unsigned short*)(ws + ((size_t)70 << 20));  // 2 MB
  unsigned short* ogb   = (unsigned short*)(ws + ((size_t)72 << 20));  // 2 MB
  unsigned short* sb    = (unsigned short*)(ws + ((size_t)74 << 20));  // 2 MB
  unsigned short* Wp    = (unsigned short*)(ws + ((size_t)76 << 20));  // 8 MB
  unsigned short* wob   = (unsigned short*)(ws + ((size_t)84 << 20));  // 2 MB
  unsigned short* wzp   = (unsigned short*)(ws + ((size_t)86 << 20));  // 4 KB
  float*          c12   = (float*)(ws + ((size_t)86 << 20) + 4096);    // 128 B
  float*          opart = (float*)(ws + ((size_t)96 << 20));           // 16 MB
  float*          mlb   = (float*)(ws + ((size_t)112 << 20));          // 256 KB
  float*          llb   = (float*)(ws + ((size_t)113 << 20));          // 256 KB

  prep_kernel<<<6144, 256, 0, stream>>>(s, wq, wk, wv, wg, wo, sb, Wp, wob);
  wzprep_kernel<<<1, 256, 0, stream>>>(wz, znw, znb, wzp, c12);
  bias_kernel<<<16384, 256, 0, stream>>>(z, wzp, c12, biasb);
  gemm_bf16<0><<<dim3(32, 16), 256, 0, stream>>>(sb, Wp, 1024, 4096, 1024, bq,
                                                 qbuf, kbuf, vTb, gbuf, nullptr);
  attn_kernel<<<dim3(64, 16), 256, 0, stream>>>(qbuf, kbuf, vTb, biasb, opart, mlb, llb);
  combine_kernel<<<1024, 256, 0, stream>>>(opart, mlb, llb, gbuf, ogb);
  gemm_bf16<1><<<dim3(8, 16), 256, 0, stream>>>(ogb, wob, 1024, 1024, 1024, nullptr,
                                                nullptr, nullptr, nullptr, nullptr, out);
}

// Round 4
// 234.710 us; speedup vs baseline: 1.1403x; 1.1053x over previous
//
#include <hip/hip_runtime.h>

typedef __attribute__((ext_vector_type(8))) short bf16x8;
typedef __attribute__((ext_vector_type(4))) float f32x4;

#define MFMA16(a,b,c) __builtin_amdgcn_mfma_f32_16x16x32_bf16(a,b,c,0,0,0)

__device__ __forceinline__ unsigned short f2bf(float f){
  unsigned int u = __float_as_uint(f);
  unsigned int r = (u + 0x7fffu + ((u >> 16) & 1u)) >> 16;
  return (unsigned short)r;
}
__device__ __forceinline__ float bf2f(unsigned short u){
  return __uint_as_float(((unsigned int)u) << 16);
}

// ---------------- prep: f32 -> bf16 conversions ----------------
__global__ __launch_bounds__(256) void prep_kernel(
    const float* __restrict__ s, const float* __restrict__ wq,
    const float* __restrict__ wk, const float* __restrict__ wv,
    const float* __restrict__ wg, const float* __restrict__ wo,
    unsigned short* __restrict__ sb, unsigned short* __restrict__ Wp,
    unsigned short* __restrict__ wob)
{
  const size_t M1 = 1u << 20;
  size_t base = ((size_t)blockIdx.x * 256 + threadIdx.x) * 4;
  const float* src; unsigned short* dst; size_t off;
  if (base < M1) { src = s; dst = sb; off = base; }
  else if (base < 5*M1) {
    size_t r = base - M1; int wsel = (int)(r >> 20);
    const float* wsrc0 = (wsel == 0) ? wq : (wsel == 1) ? wk : (wsel == 2) ? wv : wg;
    src = wsrc0; dst = Wp + ((size_t)wsel << 20); off = r & (M1 - 1);
  } else { src = wo; dst = wob; off = base - 5*M1; }
  float4 v = *(const float4*)(src + off);
  ushort4 o4;
  o4.x = f2bf(v.x); o4.y = f2bf(v.y); o4.z = f2bf(v.z); o4.w = f2bf(v.w);
  *(ushort4*)(dst + off) = o4;
}

// ---------------- wz prep: wz' = wz*w (bf16), c1=sum(wz*w), c2=sum(wz*b) ----------------
__global__ __launch_bounds__(256) void wzprep_kernel(
    const float* __restrict__ wz, const float* __restrict__ znw,
    const float* __restrict__ znb, unsigned short* __restrict__ wzp,
    float* __restrict__ c12)
{
  __shared__ float r1[256], r2[256];
  int t = threadIdx.x; int h = t >> 4; int k0 = (t & 15) * 8;
  float p1 = 0.f, p2 = 0.f;
  for (int e = 0; e < 8; e++) {
    float wv = wz[h*128 + k0 + e];
    float w = znw[k0 + e], b = znb[k0 + e];
    wzp[h*128 + k0 + e] = f2bf(wv * w);
    p1 += wv * w; p2 += wv * b;
  }
  r1[t] = p1; r2[t] = p2;
  __syncthreads();
  if ((t & 15) == 0) {
    float s1 = 0.f, s2 = 0.f;
    for (int i = 0; i < 16; i++) { s1 += r1[t + i]; s2 += r2[t + i]; }
    c12[2*h] = s1; c12[2*h + 1] = s2;
  }
}

// ---------------- bf16 GEMM: C[M][N] = A[M][K] * B[N][K]^T ----------------
// wave tile 32x64 (acc 2x4); block = 4 waves (2 row x 2 col) = 64x128 tile
template<int MODE>
__global__ __launch_bounds__(256) void gemm_bf16(
    const unsigned short* __restrict__ A, const unsigned short* __restrict__ Bm,
    int M, int N, int K,
    const float* __restrict__ bq,
    unsigned short* __restrict__ qb, unsigned short* __restrict__ kb,
    unsigned short* __restrict__ vT, unsigned short* __restrict__ gb,
    float* __restrict__ outF)
{
  int lane = threadIdx.x & 63;
  int w = threadIdx.x >> 6;
  int lr = lane & 15, lg = lane >> 4;
  int row0 = blockIdx.y * 64 + (w & 1) * 32;
  int col0 = blockIdx.x * 128 + (w >> 1) * 64;
  f32x4 acc[2][4] = {};
  for (int kk = 0; kk < K; kk += 32) {
    bf16x8 af[2], bfr[4];
    #pragma unroll
    for (int t = 0; t < 2; t++)
      af[t] = *(const bf16x8*)(A + (size_t)(row0 + t*16 + lr) * K + kk + lg*8);
    #pragma unroll
    for (int t = 0; t < 4; t++)
      bfr[t] = *(const bf16x8*)(Bm + (size_t)(col0 + t*16 + lr) * K + kk + lg*8);
    #pragma unroll
    for (int a = 0; a < 2; a++)
      #pragma unroll
      for (int b = 0; b < 4; b++)
        acc[a][b] = MFMA16(af[a], bfr[b], acc[a][b]);
  }
  #pragma unroll
  for (int a = 0; a < 2; a++)
    #pragma unroll
    for (int b = 0; b < 4; b++)
      #pragma unroll
      for (int r = 0; r < 4; r++) {
        int m = row0 + a*16 + lg*4 + r;
        int n = col0 + b*16 + lr;
        float v = acc[a][b][r];
        if (MODE == 0) {
          if (n < 1024)      { v = (v + bq[n]) * 0.125f; qb[(size_t)m*1024 + n] = f2bf(v); }
          else if (n < 2048) { kb[(size_t)m*1024 + (n-1024)] = f2bf(v); }
          else if (n < 3072) { vT[(size_t)(n-2048)*1024 + m] = f2bf(v); }
          else               { float sg = 1.f / (1.f + __expf(-v)); gb[(size_t)m*1024 + (n-3072)] = f2bf(sg); }
        } else {
          outF[(size_t)m * N + n] = v;
        }
      }
}

// ---------------- fused bias + attention ----------------
// block = 16 waves (1024 thr) = all 16 heads for one 16-query tile, one j-quarter.
// Per 64-j tile:
//   phase A: wave w computes LN(z[q0+w, j, :]) . wz' bias for all 16 heads
//            (16 positions per MFMA, 4 iters) -> LDS biasT[h][q][jpad]
//   phase B: wave w = head w does swapped-QK^T flash step with bias from LDS.
// z is read exactly once chip-wide; bias never touches HBM.
__global__ __launch_bounds__(1024, 4) void fused_attn(
    const unsigned short* __restrict__ qb, const unsigned short* __restrict__ kb,
    const unsigned short* __restrict__ vT, const float* __restrict__ z,
    const unsigned short* __restrict__ wzp, const float* __restrict__ c12,
    float* __restrict__ op, float* __restrict__ ml, float* __restrict__ ll)
{
  __shared__ float biasT[16][16][68];        // [h][q-local][j-local], pad 68 (16B-aligned, ~2-way)
  __shared__ unsigned short P[16][1024];     // per-wave P bounce, XOR-swizzled
  int w = threadIdx.x >> 6;                  // wave id = head = owned q-row
  int lane = threadIdx.x & 63;
  int jl = lane & 15, g = lane >> 4;
  int q0 = blockIdx.x * 16;
  int s = blockIdx.y;                        // j-quarter
  int h = w;
  unsigned short* Pw = P[w];

  // wz' A-fragments (rows = head, k = 128), persistent
  bf16x8 af[4];
  #pragma unroll
  for (int mk = 0; mk < 4; mk++)
    af[mk] = *(const bf16x8*)(wzp + jl*128 + mk*32 + g*8);
  // Q fragment for head h (scale 0.125 already folded in qb)
  bf16x8 aq[2];
  #pragma unroll
  for (int kh = 0; kh < 2; kh++)
    aq[kh] = *(const bf16x8*)(qb + (size_t)(q0 + jl)*1024 + h*64 + kh*32 + g*8);
  float c1r[4], c2r[4];
  #pragma unroll
  for (int r = 0; r < 4; r++) {
    c1r[r] = c12[2*(g*4 + r)];
    c2r[r] = c12[2*(g*4 + r) + 1];
  }

  f32x4 od[4] = {};
  float m = -1e30f, ss = 0.f;

  for (int t = 0; t < 4; t++) {
    int jt = s*256 + t*64;

    // ---------- phase A: bias fill for q-row q0+w, j in [jt, jt+64) ----------
    #pragma unroll
    for (int it = 0; it < 4; it++) {
      int j = jt + it*16 + jl;
      const float* zp = z + ((size_t)(q0 + w)*1024 + j)*128;
      float4 zv[8];
      #pragma unroll
      for (int mk = 0; mk < 4; mk++) {
        zv[2*mk]   = *(const float4*)(zp + mk*32 + g*8);
        zv[2*mk+1] = *(const float4*)(zp + mk*32 + g*8 + 4);
      }
      float sum = 0.f, sq = 0.f;
      #pragma unroll
      for (int u = 0; u < 8; u++) {
        float4 v = zv[u];
        sum += v.x + v.y + v.z + v.w;
        sq = fmaf(v.x, v.x, fmaf(v.y, v.y, fmaf(v.z, v.z, fmaf(v.w, v.w, sq))));
      }
      sum += __shfl_xor(sum, 16); sum += __shfl_xor(sum, 32);
      sq  += __shfl_xor(sq, 16);  sq  += __shfl_xor(sq, 32);
      float mu = sum * (1.f/128.f);
      float rs = rsqrtf(sq * (1.f/128.f) - mu*mu + 1e-5f);
      f32x4 D = {0.f, 0.f, 0.f, 0.f};
      #pragma unroll
      for (int mk = 0; mk < 4; mk++) {
        float4 a = zv[2*mk], b = zv[2*mk+1];
        bf16x8 tf;
        tf[0] = (short)f2bf(a.x); tf[1] = (short)f2bf(a.y);
        tf[2] = (short)f2bf(a.z); tf[3] = (short)f2bf(a.w);
        tf[4] = (short)f2bf(b.x); tf[5] = (short)f2bf(b.y);
        tf[6] = (short)f2bf(b.z); tf[7] = (short)f2bf(b.w);
        D = MFMA16(af[mk], tf, D);
      }
      #pragma unroll
      for (int r = 0; r < 4; r++)
        biasT[g*4 + r][w][it*16 + jl] = rs*(D[r] - mu*c1r[r]) + c2r[r];
    }
    __syncthreads();

    // ---------- phase B: attention on this 64-j tile, head h ----------
    f32x4 sc[4] = {};
    #pragma unroll
    for (int jb = 0; jb < 4; jb++)
      #pragma unroll
      for (int kh = 0; kh < 2; kh++) {
        bf16x8 bk = *(const bf16x8*)(kb + (size_t)(jt + jb*16 + jl)*1024 + h*64 + kh*32 + g*8);
        sc[jb] = MFMA16(bk, aq[kh], sc[jb]);   // swapped: rows=j, cols=q
      }
    #pragma unroll
    for (int jb = 0; jb < 4; jb++) {
      f32x4 bl = *(const f32x4*)(&biasT[h][jl][jb*16 + g*4]);
      sc[jb][0] += bl[0]; sc[jb][1] += bl[1];
      sc[jb][2] += bl[2]; sc[jb][3] += bl[3];
    }

    float mx = -1e30f;
    #pragma unroll
    for (int jb = 0; jb < 4; jb++)
      #pragma unroll
      for (int r = 0; r < 4; r++) mx = fmaxf(mx, sc[jb][r]);
    mx = fmaxf(mx, __shfl_xor(mx, 16));
    mx = fmaxf(mx, __shfl_xor(mx, 32));
    float mn = fmaxf(m, mx);
    float a = __expf(m - mn);
    m = mn;
    float rsum = 0.f;
    #pragma unroll
    for (int jb = 0; jb < 4; jb++) {
      short4 pk;
      float p0 = __expf(sc[jb][0] - mn); rsum += p0; pk.x = (short)f2bf(p0);
      float p1 = __expf(sc[jb][1] - mn); rsum += p1; pk.y = (short)f2bf(p1);
      float p2 = __expf(sc[jb][2] - mn); rsum += p2; pk.z = (short)f2bf(p2);
      float p3 = __expf(sc[jb][3] - mn); rsum += p3; pk.w = (short)f2bf(p3);
      int b = jb*2 + (g >> 1);
      int bpz = b ^ (jl & 7);
      *(short4*)(Pw + jl*64 + bpz*8 + (g & 1)*4) = pk;
    }
    ss = ss * a + rsum;   // per-lane quarter-partial (reduced over g at the end)

    float albc[4];
    #pragma unroll
    for (int r = 0; r < 4; r++) albc[r] = __shfl(a, g*4 + r);
    #pragma unroll
    for (int db = 0; db < 4; db++)
      #pragma unroll
      for (int r = 0; r < 4; r++) od[db][r] *= albc[r];

    #pragma unroll
    for (int jh = 0; jh < 2; jh++) {
      int b = jh*4 + g;
      int bpz = b ^ (jl & 7);
      bf16x8 ap = *(const bf16x8*)(Pw + jl*64 + bpz*8);
      #pragma unroll
      for (int db = 0; db < 4; db++) {
        bf16x8 bv = *(const bf16x8*)(vT + (size_t)(h*64 + db*16 + jl)*1024 + jt + jh*32 + g*8);
        od[db] = MFMA16(ap, bv, od[db]);
      }
    }
    __syncthreads();   // biasT reused next tile
  }

  // reduce ss across the 4 replicated lane-groups (same jl)
  ss += __shfl_xor(ss, 16);
  ss += __shfl_xor(ss, 32);

  size_t base = ((size_t)(s*16 + h) * 1024);
  #pragma unroll
  for (int db = 0; db < 4; db++)
    #pragma unroll
    for (int r = 0; r < 4; r++) {
      int q = q0 + g*4 + r;
      op[(base + q)*64 + db*16 + jl] = od[db][r];
    }
  if (g == 0) {
    ml[base + q0 + jl] = m;
    ll[base + q0 + jl] = ss;
  }
}

// ---------------- combine: merge 4 j-split partials, gate, bf16 ----------------
__global__ __launch_bounds__(256) void combine_kernel(
    const float* __restrict__ op, const float* __restrict__ ml,
    const float* __restrict__ ll, const unsigned short* __restrict__ gb,
    unsigned short* __restrict__ og)
{
  int t = blockIdx.x * 256 + threadIdx.x;   // over 16h * 1024q * 16d4
  int d4 = t & 15;
  int q = (t >> 4) & 1023;
  int h = t >> 14;

  float mv[4], lv[4];
  float mstar = -1e30f;
  #pragma unroll
  for (int s = 0; s < 4; s++) {
    mv[s] = ml[(size_t)(s*16 + h)*1024 + q];
    lv[s] = ll[(size_t)(s*16 + h)*1024 + q];
    mstar = fmaxf(mstar, mv[s]);
  }
  float lsum = 0.f;
  float ws[4];
  #pragma unroll
  for (int s = 0; s < 4; s++) {
    ws[s] = __expf(mv[s] - mstar);
    lsum = fmaf(ws[s], lv[s], lsum);
  }
  float inv = 1.f / lsum;

  float4 o = {0.f, 0.f, 0.f, 0.f};
  #pragma unroll
  for (int s = 0; s < 4; s++) {
    float4 p = *(const float4*)(op + ((size_t)(s*16 + h)*1024 + q)*64 + d4*4);
    o.x = fmaf(ws[s], p.x, o.x); o.y = fmaf(ws[s], p.y, o.y);
    o.z = fmaf(ws[s], p.z, o.z); o.w = fmaf(ws[s], p.w, o.w);
  }
  ushort4 gv = *(const ushort4*)(gb + (size_t)q*1024 + h*64 + d4*4);
  ushort4 r;
  r.x = f2bf(o.x * inv * bf2f(gv.x));
  r.y = f2bf(o.y * inv * bf2f(gv.y));
  r.z = f2bf(o.z * inv * bf2f(gv.z));
  r.w = f2bf(o.w * inv * bf2f(gv.w));
  *(ushort4*)(og + (size_t)q*1024 + h*64 + d4*4) = r;
}

extern "C" void kernel_launch(void* const* d_in, const int* in_sizes, int n_in,
                              void* d_out, int out_size, void* d_ws, size_t ws_size,
                              hipStream_t stream) {
  const float* s   = (const float*)d_in[0];
  const float* z   = (const float*)d_in[1];
  const float* wq  = (const float*)d_in[2];
  const float* bq  = (const float*)d_in[3];
  const float* wk  = (const float*)d_in[4];
  const float* wv  = (const float*)d_in[5];
  const float* wg  = (const float*)d_in[6];
  const float* znw = (const float*)d_in[7];
  const float* znb = (const float*)d_in[8];
  const float* wz  = (const float*)d_in[9];
  const float* wo  = (const float*)d_in[10];
  float* out = (float*)d_out;

  char* ws = (char*)d_ws;
  unsigned short* qbuf  = (unsigned short*)(ws + ((size_t)64 << 20));  // 2 MB
  unsigned short* kbuf  = (unsigned short*)(ws + ((size_t)66 << 20));  // 2 MB
  unsigned short* vTb   = (unsigned short*)(ws + ((size_t)68 << 20));  // 2 MB
  unsigned short* gbuf  = (unsigned short*)(ws + ((size_t)70 << 20));  // 2 MB
  unsigned short* ogb   = (unsigned short*)(ws + ((size_t)72 << 20));  // 2 MB
  unsigned short* sb    = (unsigned short*)(ws + ((size_t)74 << 20));  // 2 MB
  unsigned short* Wp    = (unsigned short*)(ws + ((size_t)76 << 20));  // 8 MB
  unsigned short* wob   = (unsigned short*)(ws + ((size_t)84 << 20));  // 2 MB
  unsigned short* wzp   = (unsigned short*)(ws + ((size_t)86 << 20));  // 4 KB
  float*          c12   = (float*)(ws + ((size_t)86 << 20) + 4096);    // 128 B
  float*          opart = (float*)(ws + ((size_t)96 << 20));           // 16 MB
  float*          mlb   = (float*)(ws + ((size_t)112 << 20));          // 256 KB
  float*          llb   = (float*)(ws + ((size_t)113 << 20));          // 256 KB

  prep_kernel<<<6144, 256, 0, stream>>>(s, wq, wk, wv, wg, wo, sb, Wp, wob);
  wzprep_kernel<<<1, 256, 0, stream>>>(wz, znw, znb, wzp, c12);
  gemm_bf16<0><<<dim3(32, 16), 256, 0, stream>>>(sb, Wp, 1024, 4096, 1024, bq,
                                                 qbuf, kbuf, vTb, gbuf, nullptr);
  fused_attn<<<dim3(64, 4), 1024, 0, stream>>>(qbuf, kbuf, vTb, z, wzp, c12,
                                               opart, mlb, llb);
  combine_kernel<<<1024, 256, 0, stream>>>(opart, mlb, llb, gbuf, ogb);
  gemm_bf16<1><<<dim3(8, 16), 256, 0, stream>>>(ogb, wob, 1024, 1024, 1024, nullptr,
                                                nullptr, nullptr, nullptr, nullptr, out);
}

// Round 5
// 229.127 us; speedup vs baseline: 1.1681x; 1.0244x over previous
//
#include <hip/hip_runtime.h>

typedef __attribute__((ext_vector_type(8))) short bf16x8;
typedef __attribute__((ext_vector_type(4))) float f32x4;

#define MFMA16(a,b,c) __builtin_amdgcn_mfma_f32_16x16x32_bf16(a,b,c,0,0,0)

__device__ __forceinline__ unsigned short f2bf(float f){
  unsigned int u = __float_as_uint(f);
  unsigned int r = (u + 0x7fffu + ((u >> 16) & 1u)) >> 16;
  return (unsigned short)r;
}
__device__ __forceinline__ float bf2f(unsigned short u){
  return __uint_as_float(((unsigned int)u) << 16);
}

// ---------------- prep: f32 -> bf16 conversions (+ embedded wz prep) ----------------
__global__ __launch_bounds__(256) void prep_kernel(
    const float* __restrict__ s, const float* __restrict__ wq,
    const float* __restrict__ wk, const float* __restrict__ wv,
    const float* __restrict__ wg, const float* __restrict__ wo,
    const float* __restrict__ wz, const float* __restrict__ znw,
    const float* __restrict__ znb,
    unsigned short* __restrict__ sb, unsigned short* __restrict__ Wp,
    unsigned short* __restrict__ wob,
    unsigned short* __restrict__ wzp, float* __restrict__ c12)
{
  __shared__ float r1[256], r2[256];
  if (blockIdx.x == 6144) {
    // wz prep: wz' = wz*w (bf16), c1=sum(wz*w), c2=sum(wz*b)
    int t = threadIdx.x; int h = t >> 4; int k0 = (t & 15) * 8;
    float p1 = 0.f, p2 = 0.f;
    for (int e = 0; e < 8; e++) {
      float wvv = wz[h*128 + k0 + e];
      float w = znw[k0 + e], b = znb[k0 + e];
      wzp[h*128 + k0 + e] = f2bf(wvv * w);
      p1 += wvv * w; p2 += wvv * b;
    }
    r1[t] = p1; r2[t] = p2;
    __syncthreads();
    if ((t & 15) == 0) {
      float s1 = 0.f, s2 = 0.f;
      for (int i = 0; i < 16; i++) { s1 += r1[t + i]; s2 += r2[t + i]; }
      c12[2*h] = s1; c12[2*h + 1] = s2;
    }
    return;
  }
  const size_t M1 = 1u << 20;
  size_t base = ((size_t)blockIdx.x * 256 + threadIdx.x) * 4;
  const float* src; unsigned short* dst; size_t off;
  if (base < M1) { src = s; dst = sb; off = base; }
  else if (base < 5*M1) {
    size_t r = base - M1; int wsel = (int)(r >> 20);
    const float* wsrc0 = (wsel == 0) ? wq : (wsel == 1) ? wk : (wsel == 2) ? wv : wg;
    src = wsrc0; dst = Wp + ((size_t)wsel << 20); off = r & (M1 - 1);
  } else { src = wo; dst = wob; off = base - 5*M1; }
  float4 v = *(const float4*)(src + off);
  ushort4 o4;
  o4.x = f2bf(v.x); o4.y = f2bf(v.y); o4.z = f2bf(v.z); o4.w = f2bf(v.w);
  *(ushort4*)(dst + off) = o4;
}

// ---------------- bf16 GEMM: C[M][N] = A[M][K] * B[N][K]^T ----------------
// wave tile 32x64 (acc 2x4); block = 4 waves (2 row x 2 col) = 64x128 tile
template<int MODE>
__global__ __launch_bounds__(256) void gemm_bf16(
    const unsigned short* __restrict__ A, const unsigned short* __restrict__ Bm,
    int M, int N, int K,
    const float* __restrict__ bq,
    unsigned short* __restrict__ qb, unsigned short* __restrict__ kb,
    unsigned short* __restrict__ vT, unsigned short* __restrict__ gb,
    float* __restrict__ outF)
{
  int lane = threadIdx.x & 63;
  int w = threadIdx.x >> 6;
  int lr = lane & 15, lg = lane >> 4;
  int row0 = blockIdx.y * 64 + (w & 1) * 32;
  int col0 = blockIdx.x * 128 + (w >> 1) * 64;
  f32x4 acc[2][4] = {};
  for (int kk = 0; kk < K; kk += 32) {
    bf16x8 af[2], bfr[4];
    #pragma unroll
    for (int t = 0; t < 2; t++)
      af[t] = *(const bf16x8*)(A + (size_t)(row0 + t*16 + lr) * K + kk + lg*8);
    #pragma unroll
    for (int t = 0; t < 4; t++)
      bfr[t] = *(const bf16x8*)(Bm + (size_t)(col0 + t*16 + lr) * K + kk + lg*8);
    #pragma unroll
    for (int a = 0; a < 2; a++)
      #pragma unroll
      for (int b = 0; b < 4; b++)
        acc[a][b] = MFMA16(af[a], bfr[b], acc[a][b]);
  }
  #pragma unroll
  for (int a = 0; a < 2; a++)
    #pragma unroll
    for (int b = 0; b < 4; b++)
      #pragma unroll
      for (int r = 0; r < 4; r++) {
        int m = row0 + a*16 + lg*4 + r;
        int n = col0 + b*16 + lr;
        float v = acc[a][b][r];
        if (MODE == 0) {
          if (n < 1024)      { v = (v + bq[n]) * 0.125f; qb[(size_t)m*1024 + n] = f2bf(v); }
          else if (n < 2048) { kb[(size_t)m*1024 + (n-1024)] = f2bf(v); }
          else if (n < 3072) { vT[(size_t)(n-2048)*1024 + m] = f2bf(v); }
          else               { float sg = 1.f / (1.f + __expf(-v)); gb[(size_t)m*1024 + (n-3072)] = f2bf(sg); }
        } else {
          outF[(size_t)m * N + n] = v;
        }
      }
}

// ---------------- fused bias + attention ----------------
// block = 16 waves (1024 thr) = all 16 heads for one 16-query tile, one j-quarter.
// VGPR budget: 1024-thr block (4 waves/SIMD) caps VGPR at 128 -> phase A packs
// z to bf16 per-float4 (stats accumulated in f32 first), no f32 zv[8] live set.
__global__ __launch_bounds__(1024, 4) void fused_attn(
    const unsigned short* __restrict__ qb, const unsigned short* __restrict__ kb,
    const unsigned short* __restrict__ vT, const float* __restrict__ z,
    const unsigned short* __restrict__ wzp, const float* __restrict__ c12,
    float* __restrict__ op, float* __restrict__ ml, float* __restrict__ ll)
{
  __shared__ float biasT[16][17][68];        // [h][q-local(pad17)][j-local]
  __shared__ unsigned short P[16][1024];     // per-wave P bounce, XOR-swizzled
  int w = threadIdx.x >> 6;                  // wave id = head = owned q-row
  int lane = threadIdx.x & 63;
  int jl = lane & 15, g = lane >> 4;
  int q0 = blockIdx.x * 16;
  int s = blockIdx.y;                        // j-quarter
  int h = w;
  unsigned short* Pw = P[w];

  // wz' A-fragments (rows = head, k = 128), persistent
  bf16x8 af[4];
  #pragma unroll
  for (int mk = 0; mk < 4; mk++)
    af[mk] = *(const bf16x8*)(wzp + jl*128 + mk*32 + g*8);
  // Q fragment for head h (scale 0.125 already folded in qb)
  bf16x8 aq[2];
  #pragma unroll
  for (int kh = 0; kh < 2; kh++)
    aq[kh] = *(const bf16x8*)(qb + (size_t)(q0 + jl)*1024 + h*64 + kh*32 + g*8);
  float c1r[4], c2r[4];
  #pragma unroll
  for (int r = 0; r < 4; r++) {
    c1r[r] = c12[2*(g*4 + r)];
    c2r[r] = c12[2*(g*4 + r) + 1];
  }

  f32x4 od[4] = {};
  float m = -1e30f, ss = 0.f;

  #pragma unroll 1
  for (int t = 0; t < 4; t++) {
    int jt = s*256 + t*64;

    // ---------- phase A: bias fill for q-row q0+w, j in [jt, jt+64) ----------
    #pragma unroll 1
    for (int it = 0; it < 4; it++) {
      int j = jt + it*16 + jl;
      const float* zp = z + ((size_t)(q0 + w)*1024 + j)*128;
      bf16x8 tf[4];
      float sum = 0.f, sq = 0.f;
      #pragma unroll
      for (int mk = 0; mk < 4; mk++) {
        float4 a = *(const float4*)(zp + mk*32 + g*8);
        float4 b = *(const float4*)(zp + mk*32 + g*8 + 4);
        sum += a.x + a.y + a.z + a.w + b.x + b.y + b.z + b.w;
        sq = fmaf(a.x, a.x, fmaf(a.y, a.y, fmaf(a.z, a.z, fmaf(a.w, a.w, sq))));
        sq = fmaf(b.x, b.x, fmaf(b.y, b.y, fmaf(b.z, b.z, fmaf(b.w, b.w, sq))));
        bf16x8 tv;
        tv[0] = (short)f2bf(a.x); tv[1] = (short)f2bf(a.y);
        tv[2] = (short)f2bf(a.z); tv[3] = (short)f2bf(a.w);
        tv[4] = (short)f2bf(b.x); tv[5] = (short)f2bf(b.y);
        tv[6] = (short)f2bf(b.z); tv[7] = (short)f2bf(b.w);
        tf[mk] = tv;
      }
      sum += __shfl_xor(sum, 16); sum += __shfl_xor(sum, 32);
      sq  += __shfl_xor(sq, 16);  sq  += __shfl_xor(sq, 32);
      float mu = sum * (1.f/128.f);
      float rs = rsqrtf(sq * (1.f/128.f) - mu*mu + 1e-5f);
      f32x4 D = {0.f, 0.f, 0.f, 0.f};
      #pragma unroll
      for (int mk = 0; mk < 4; mk++)
        D = MFMA16(af[mk], tf[mk], D);
      #pragma unroll
      for (int r = 0; r < 4; r++)
        biasT[g*4 + r][w][it*16 + jl] = rs*(D[r] - mu*c1r[r]) + c2r[r];
    }
    __syncthreads();

    // ---------- phase B: attention on this 64-j tile, head h ----------
    f32x4 sc[4] = {};
    #pragma unroll
    for (int jb = 0; jb < 4; jb++)
      #pragma unroll
      for (int kh = 0; kh < 2; kh++) {
        bf16x8 bk = *(const bf16x8*)(kb + (size_t)(jt + jb*16 + jl)*1024 + h*64 + kh*32 + g*8);
        sc[jb] = MFMA16(bk, aq[kh], sc[jb]);   // swapped: rows=j, cols=q
      }
    #pragma unroll
    for (int jb = 0; jb < 4; jb++) {
      f32x4 bl = *(const f32x4*)(&biasT[h][jl][jb*16 + g*4]);
      sc[jb][0] += bl[0]; sc[jb][1] += bl[1];
      sc[jb][2] += bl[2]; sc[jb][3] += bl[3];
    }

    float mx = -1e30f;
    #pragma unroll
    for (int jb = 0; jb < 4; jb++)
      #pragma unroll
      for (int r = 0; r < 4; r++) mx = fmaxf(mx, sc[jb][r]);
    mx = fmaxf(mx, __shfl_xor(mx, 16));
    mx = fmaxf(mx, __shfl_xor(mx, 32));
    float mn = fmaxf(m, mx);
    float a = __expf(m - mn);
    m = mn;
    float rsum = 0.f;
    #pragma unroll
    for (int jb = 0; jb < 4; jb++) {
      short4 pk;
      float p0 = __expf(sc[jb][0] - mn); rsum += p0; pk.x = (short)f2bf(p0);
      float p1 = __expf(sc[jb][1] - mn); rsum += p1; pk.y = (short)f2bf(p1);
      float p2 = __expf(sc[jb][2] - mn); rsum += p2; pk.z = (short)f2bf(p2);
      float p3 = __expf(sc[jb][3] - mn); rsum += p3; pk.w = (short)f2bf(p3);
      int b = jb*2 + (g >> 1);
      int bpz = b ^ (jl & 7);
      *(short4*)(Pw + jl*64 + bpz*8 + (g & 1)*4) = pk;
    }
    ss = ss * a + rsum;   // per-lane quarter-partial (reduced over g at the end)

    float albc[4];
    #pragma unroll
    for (int r = 0; r < 4; r++) albc[r] = __shfl(a, g*4 + r);
    #pragma unroll
    for (int db = 0; db < 4; db++)
      #pragma unroll
      for (int r = 0; r < 4; r++) od[db][r] *= albc[r];

    #pragma unroll
    for (int jh = 0; jh < 2; jh++) {
      int b = jh*4 + g;
      int bpz = b ^ (jl & 7);
      bf16x8 ap = *(const bf16x8*)(Pw + jl*64 + bpz*8);
      #pragma unroll
      for (int db = 0; db < 4; db++) {
        bf16x8 bv = *(const bf16x8*)(vT + (size_t)(h*64 + db*16 + jl)*1024 + jt + jh*32 + g*8);
        od[db] = MFMA16(ap, bv, od[db]);
      }
    }
    __syncthreads();   // biasT reused next tile
  }

  // reduce ss across the 4 replicated lane-groups (same jl)
  ss += __shfl_xor(ss, 16);
  ss += __shfl_xor(ss, 32);

  size_t base = ((size_t)(s*16 + h) * 1024);
  #pragma unroll
  for (int db = 0; db < 4; db++)
    #pragma unroll
    for (int r = 0; r < 4; r++) {
      int q = q0 + g*4 + r;
      op[(base + q)*64 + db*16 + jl] = od[db][r];
    }
  if (g == 0) {
    ml[base + q0 + jl] = m;
    ll[base + q0 + jl] = ss;
  }
}

// ---------------- combine: merge 4 j-split partials, gate, bf16 ----------------
__global__ __launch_bounds__(256) void combine_kernel(
    const float* __restrict__ op, const float* __restrict__ ml,
    const float* __restrict__ ll, const unsigned short* __restrict__ gb,
    unsigned short* __restrict__ og)
{
  int t = blockIdx.x * 256 + threadIdx.x;   // over 16h * 1024q * 16d4
  int d4 = t & 15;
  int q = (t >> 4) & 1023;
  int h = t >> 14;

  float mv[4], lv[4];
  float mstar = -1e30f;
  #pragma unroll
  for (int s = 0; s < 4; s++) {
    mv[s] = ml[(size_t)(s*16 + h)*1024 + q];
    lv[s] = ll[(size_t)(s*16 + h)*1024 + q];
    mstar = fmaxf(mstar, mv[s]);
  }
  float lsum = 0.f;
  float ws[4];
  #pragma unroll
  for (int s = 0; s < 4; s++) {
    ws[s] = __expf(mv[s] - mstar);
    lsum = fmaf(ws[s], lv[s], lsum);
  }
  float inv = 1.f / lsum;

  float4 o = {0.f, 0.f, 0.f, 0.f};
  #pragma unroll
  for (int s = 0; s < 4; s++) {
    float4 p = *(const float4*)(op + ((size_t)(s*16 + h)*1024 + q)*64 + d4*4);
    o.x = fmaf(ws[s], p.x, o.x); o.y = fmaf(ws[s], p.y, o.y);
    o.z = fmaf(ws[s], p.z, o.z); o.w = fmaf(ws[s], p.w, o.w);
  }
  ushort4 gv = *(const ushort4*)(gb + (size_t)q*1024 + h*64 + d4*4);
  ushort4 r;
  r.x = f2bf(o.x * inv * bf2f(gv.x));
  r.y = f2bf(o.y * inv * bf2f(gv.y));
  r.z = f2bf(o.z * inv * bf2f(gv.z));
  r.w = f2bf(o.w * inv * bf2f(gv.w));
  *(ushort4*)(og + (size_t)q*1024 + h*64 + d4*4) = r;
}

extern "C" void kernel_launch(void* const* d_in, const int* in_sizes, int n_in,
                              void* d_out, int out_size, void* d_ws, size_t ws_size,
                              hipStream_t stream) {
  const float* s   = (const float*)d_in[0];
  const float* z   = (const float*)d_in[1];
  const float* wq  = (const float*)d_in[2];
  const float* bq  = (const float*)d_in[3];
  const float* wk  = (const float*)d_in[4];
  const float* wv  = (const float*)d_in[5];
  const float* wg  = (const float*)d_in[6];
  const float* znw = (const float*)d_in[7];
  const float* znb = (const float*)d_in[8];
  const float* wz  = (const float*)d_in[9];
  const float* wo  = (const float*)d_in[10];
  float* out = (float*)d_out;

  char* ws = (char*)d_ws;
  unsigned short* qbuf  = (unsigned short*)(ws + ((size_t)64 << 20));  // 2 MB
  unsigned short* kbuf  = (unsigned short*)(ws + ((size_t)66 << 20));  // 2 MB
  unsigned short* vTb   = (unsigned short*)(ws + ((size_t)68 << 20));  // 2 MB
  unsigned short* gbuf  = (unsigned short*)(ws + ((size_t)70 << 20));  // 2 MB
  unsigned short* ogb   = (unsigned short*)(ws + ((size_t)72 << 20));  // 2 MB
  unsigned short* sb    = (unsigned short*)(ws + ((size_t)74 << 20));  // 2 MB
  unsigned short* Wp    = (unsigned short*)(ws + ((size_t)76 << 20));  // 8 MB
  unsigned short* wob   = (unsigned short*)(ws + ((size_t)84 << 20));  // 2 MB
  unsigned short* wzp   = (unsigned short*)(ws + ((size_t)86 << 20));  // 4 KB
  float*          c12   = (float*)(ws + ((size_t)86 << 20) + 4096);    // 128 B
  float*          opart = (float*)(ws + ((size_t)96 << 20));           // 16 MB
  float*          mlb   = (float*)(ws + ((size_t)112 << 20));          // 256 KB
  float*          llb   = (float*)(ws + ((size_t)113 << 20));          // 256 KB

  prep_kernel<<<6145, 256, 0, stream>>>(s, wq, wk, wv, wg, wo, wz, znw, znb,
                                        sb, Wp, wob, wzp, c12);
  gemm_bf16<0><<<dim3(32, 16), 256, 0, stream>>>(sb, Wp, 1024, 4096, 1024, bq,
                                                 qbuf, kbuf, vTb, gbuf, nullptr);
  fused_attn<<<dim3(64, 4), 1024, 0, stream>>>(qbuf, kbuf, vTb, z, wzp, c12,
                                               opart, mlb, llb);
  combine_kernel<<<1024, 256, 0, stream>>>(opart, mlb, llb, gbuf, ogb);
  gemm_bf16<1><<<dim3(8, 16), 256, 0, stream>>>(ogb, wob, 1024, 1024, 1024, nullptr,
                                                nullptr, nullptr, nullptr, nullptr, out);
}